// Round 5
// baseline (686.858 us; speedup 1.0000x reference)
//
#include <hip/hip_runtime.h>
#include <math.h>
#include <stdint.h>

#define T_SEQ 2048
#define DMODEL 2048
#define DLAT 1024
#define NH 16
#define DH 128
#define BATCH 2
#define MTOT (BATCH * T_SEQ)   // 4096 rows total

typedef float f32x4 __attribute__((ext_vector_type(4)));
typedef __bf16 bf16x8 __attribute__((ext_vector_type(8)));

__device__ __forceinline__ unsigned short f2bf(float f) {
    return __builtin_bit_cast(unsigned short, (__bf16)f);   // RNE native cvt
}

#define EXP2F(x) __builtin_amdgcn_exp2f(x)

// 16-lane (row) reductions via DPP: quad_perm xor1, xor2, row_ror:4, row_ror:8
__device__ __forceinline__ float red16_max(float v) {
    int x = __builtin_bit_cast(int, v);
    v = fmaxf(v, __builtin_bit_cast(float, __builtin_amdgcn_update_dpp(x, x, 0xB1, 0xf, 0xf, false)));
    x = __builtin_bit_cast(int, v);
    v = fmaxf(v, __builtin_bit_cast(float, __builtin_amdgcn_update_dpp(x, x, 0x4E, 0xf, 0xf, false)));
    x = __builtin_bit_cast(int, v);
    v = fmaxf(v, __builtin_bit_cast(float, __builtin_amdgcn_update_dpp(x, x, 0x124, 0xf, 0xf, false)));
    x = __builtin_bit_cast(int, v);
    v = fmaxf(v, __builtin_bit_cast(float, __builtin_amdgcn_update_dpp(x, x, 0x128, 0xf, 0xf, false)));
    return v;
}
__device__ __forceinline__ float red16_sum(float v) {
    int x = __builtin_bit_cast(int, v);
    v += __builtin_bit_cast(float, __builtin_amdgcn_update_dpp(x, x, 0xB1, 0xf, 0xf, false));
    x = __builtin_bit_cast(int, v);
    v += __builtin_bit_cast(float, __builtin_amdgcn_update_dpp(x, x, 0x4E, 0xf, 0xf, false));
    x = __builtin_bit_cast(int, v);
    v += __builtin_bit_cast(float, __builtin_amdgcn_update_dpp(x, x, 0x124, 0xf, 0xf, false));
    x = __builtin_bit_cast(int, v);
    v += __builtin_bit_cast(float, __builtin_amdgcn_update_dpp(x, x, 0x128, 0xf, 0xf, false));
    return v;
}

// async global->LDS, 16B per lane (dest must be linear: wave base + lane*16)
#define GLL16(g, l) __builtin_amdgcn_global_load_lds( \
    (const __attribute__((address_space(1))) unsigned int*)(g), \
    (__attribute__((address_space(3))) unsigned int*)(l), 16, 0, 0)

// ---------------- RoPE tables: cos/sin [T][64] fp32 ----------------
__global__ void rope_table_kernel(float* __restrict__ cosb, float* __restrict__ sinb) {
    int idx = blockIdx.x * blockDim.x + threadIdx.x;
    if (idx >= T_SEQ * 64) return;
    int t = idx >> 6;
    int i = idx & 63;
    float inv = expf(-((2.0f * (float)i) / 128.0f) * logf(10000.0f));
    float ang = (float)t * inv;
    cosb[idx] = cosf(ang);
    sinb[idx] = sinf(ang);
}

// ---------------- fp32 -> bf16 elementwise (x) ----------------
__global__ void conv_f2b_kernel(const float* __restrict__ s, unsigned short* __restrict__ d) {
    int i = (blockIdx.x * blockDim.x + threadIdx.x) * 4;
    float4 v = *(const float4*)(s + i);
    ushort4 o;
    o.x = f2bf(v.x); o.y = f2bf(v.y); o.z = f2bf(v.z); o.w = f2bf(v.w);
    *(ushort4*)(d + i) = o;
}

// ---------------- all 4 weights: fp32 [R][C] -> bf16 [C][R] in one launch ----
// tiles: wq 4096 | w_down 2048 | w_up 4096 | wo 4096  (32x32 tiles, 256 thr)
__global__ __launch_bounds__(256)
void transpose_all_kernel(const float* __restrict__ wq, const float* __restrict__ wdn,
                          const float* __restrict__ wup, const float* __restrict__ wo,
                          unsigned short* __restrict__ wqT, unsigned short* __restrict__ wdT,
                          unsigned short* __restrict__ wuT, unsigned short* __restrict__ woT) {
    const int tile = blockIdx.x;
    const float* src; unsigned short* dst; int R, C, local;
    if (tile < 4096)       { src = wq;  dst = wqT; R = 2048; C = 2048; local = tile; }
    else if (tile < 6144)  { src = wdn; dst = wdT; R = 2048; C = 1024; local = tile - 4096; }
    else if (tile < 10240) { src = wup; dst = wuT; R = 1024; C = 4096; local = tile - 6144; }
    else                   { src = wo;  dst = woT; R = 2048; C = 2048; local = tile - 10240; }
    const int ctiles = C >> 5;
    const int c0 = (local & (ctiles - 1)) * 32;    // ctiles is pow2
    const int r0 = (local / ctiles) * 32;
    __shared__ unsigned short t16[32][33];
    const int tx = threadIdx.x & 31, ty = threadIdx.x >> 5;
#pragma unroll
    for (int i = 0; i < 32; i += 8)
        t16[ty + i][tx] = f2bf(src[(size_t)(r0 + ty + i) * C + c0 + tx]);
    __syncthreads();
#pragma unroll
    for (int i = 0; i < 32; i += 8)
        dst[(size_t)(c0 + ty + i) * R + r0 + tx] = t16[tx][ty + i];
}

// ---------------- bf16 [R][C] -> bf16 [C][R] transpose (V -> V^T) ----------------
__global__ void transpose_b2b_kernel(const unsigned short* __restrict__ src, unsigned short* __restrict__ dst,
                                     int R, int C) {
    __shared__ unsigned short tile[32][33];
    int tx = threadIdx.x & 31, ty = threadIdx.x >> 5;
    int r0 = blockIdx.y * 32, c0 = blockIdx.x * 32;
#pragma unroll
    for (int i = 0; i < 32; i += 8)
        tile[ty + i][tx] = src[(size_t)(r0 + ty + i) * C + c0 + tx];
    __syncthreads();
#pragma unroll
    for (int i = 0; i < 32; i += 8)
        dst[(size_t)(c0 + ty + i) * R + r0 + tx] = tile[tx][ty + i];
}

// ---------------- bf16 MFMA GEMM: C[M,N] = A[M,K] * BT[N,K]^T ----------------
// 128x128 tile, BK=32, 256 thr (4 waves 2x2), wave = 64x64 = 4x4 frags of 16x16x32.
// EPI: 2 = K(RoPE)/V split bf16, 3 = fp32 store,
//      4 = fused q/ckv: col<2048 -> RoPE -> *SC2 -> C0 (stride 2048); else -> C1 (stride 1024)
template <int EPI>
__global__ __launch_bounds__(256)
void gemm_bf16_kernel(const unsigned short* __restrict__ A, const unsigned short* __restrict__ BT,
                      void* __restrict__ C0, void* __restrict__ C1,
                      const float* __restrict__ cosb, const float* __restrict__ sinb,
                      int M, int N, int K) {
    __shared__ unsigned short As[128 * 32];
    __shared__ unsigned short Bs[128 * 32];
    const int t = threadIdx.x;
    const int w = t >> 6, l = t & 63;
    const int wr = w >> 1, wc = w & 1;
    const int lr = l & 15, lg = l >> 4;
    const int m0 = blockIdx.y * 128, n0 = blockIdx.x * 128;

    f32x4 acc[4][4] = {{}};

    const unsigned short* aP  = A  + (size_t)(m0 + (t >> 2)) * K + (t & 3) * 8;
    const unsigned short* aP2 = aP + (size_t)64 * K;
    const unsigned short* bP  = BT + (size_t)(n0 + (t >> 2)) * K + (t & 3) * 8;
    const unsigned short* bP2 = bP + (size_t)64 * K;

    for (int k0 = 0; k0 < K; k0 += 32) {
        __syncthreads();                       // protect previous iteration's reads
        GLL16(aP  + k0, &As[t * 8]);
        GLL16(aP2 + k0, &As[2048 + t * 8]);
        GLL16(bP  + k0, &Bs[t * 8]);
        GLL16(bP2 + k0, &Bs[2048 + t * 8]);
        __syncthreads();                       // drains vmcnt (loads landed)

        bf16x8 af[4], bfr[4];
#pragma unroll
        for (int i = 0; i < 4; ++i)
            af[i] = *(const bf16x8*)&As[(wr * 64 + i * 16 + lr) * 32 + lg * 8];
#pragma unroll
        for (int j = 0; j < 4; ++j)
            bfr[j] = *(const bf16x8*)&Bs[(wc * 64 + j * 16 + lr) * 32 + lg * 8];
#pragma unroll
        for (int i = 0; i < 4; ++i)
#pragma unroll
            for (int j = 0; j < 4; ++j)
                acc[i][j] = __builtin_amdgcn_mfma_f32_16x16x32_bf16(af[i], bfr[j], acc[i][j], 0, 0, 0);
    }

    const float SC2 = 0.08838834764831845f * 1.44269504089f;  // 1/sqrt(128)*log2e (q prescale)
    const bool is_v  = (EPI == 2) && ((n0 & 128) != 0);    // block-uniform
    const bool is_cv = (EPI == 4) && (n0 >= 2048);         // fused: c_kv half
#pragma unroll
    for (int i = 0; i < 4; ++i) {
#pragma unroll
        for (int j = 0; j < 4; ++j) {
#pragma unroll
            for (int rr = 0; rr < 4; ++rr) {
                const int row_g = m0 + wr * 64 + i * 16 + lg * 4 + rr;
                const int col_g = n0 + wc * 64 + j * 16 + lr;
                float v = acc[i][j][rr];
                if (EPI == 2) {
                    float res = v;
                    if (!is_v) {  // K half -> RoPE
                        float o_ = __shfl_xor(v, 1);
                        int d = col_g & 127;
                        int tp = row_g & (T_SEQ - 1);
                        float c = cosb[tp * 64 + (d >> 1)];
                        float s = sinb[tp * 64 + (d >> 1)];
                        res = (lr & 1) ? (o_ * s + v * c) : (v * c - o_ * s);
                    }
                    int dcol = ((col_g >> 8) << 7) | (col_g & 127);  // head*128 + d
                    unsigned short* dst = is_v ? (unsigned short*)C1 : (unsigned short*)C0;
                    dst[(size_t)row_g * DMODEL + dcol] = f2bf(res);
                } else if (EPI == 3) {  // fp32 final
                    ((float*)C0)[(size_t)row_g * N + col_g] = v;
                } else {  // EPI == 4 fused q / c_kv
                    if (!is_cv) {       // q half -> RoPE -> prescale -> C0 [.][2048]
                        float o_ = __shfl_xor(v, 1);
                        int d = col_g & 127;
                        int tp = row_g & (T_SEQ - 1);
                        float c = cosb[tp * 64 + (d >> 1)];
                        float s = sinb[tp * 64 + (d >> 1)];
                        float res = (lr & 1) ? (o_ * s + v * c) : (v * c - o_ * s);
                        ((unsigned short*)C0)[(size_t)row_g * DMODEL + col_g] = f2bf(res * SC2);
                    } else {            // c_kv -> C1 [.][1024]
                        ((unsigned short*)C1)[(size_t)row_g * DLAT + (col_g - 2048)] = f2bf(v);
                    }
                }
            }
        }
    }
}

// ---------------- staged bf16 MFMA causal flash attention ----------------
// grid (B*NH, 16), 256 thr = 4 waves, 128 q-rows/block. 64-key tiles, K+V
// single-buffered LDS (40KB -> 4 blocks/CU; TLP hides stage latency).
// XOR-swizzled LDS via pre-swizzled global_load_lds source. LPT order.
// Q is pre-scaled by scale*log2e in the GEMM epilogue -> softmax in exp2
// domain with defer-rescale (THR=8); DPP row reductions; setprio MFMA.
__global__ __launch_bounds__(256, 4)
void attn_mfma2_kernel(const unsigned short* __restrict__ qb, const unsigned short* __restrict__ kb,
                       const unsigned short* __restrict__ vT, unsigned short* __restrict__ ob) {
    __shared__ __align__(16) unsigned short Ks[64 * 128];      // 16KB
    __shared__ __align__(16) unsigned short Vs[128 * 64];      // 16KB (V^T: d-major)
    __shared__ __align__(16) unsigned short Ps[4][16][64];     // 8KB, per-wave P buf

    const int bh = blockIdx.x;
    const int b = bh >> 4, h = bh & 15;
    const int qt = 15 - blockIdx.y;           // longest blocks first
    const int t = threadIdx.x;
    const int w = t >> 6, l = t & 63;
    const int lr = l & 15, lg = l >> 4;

    const unsigned short* kbase = kb + (size_t)(b * T_SEQ) * DMODEL + h * DH;
    const unsigned short* vbase = vT + (size_t)(h * DH) * MTOT + (size_t)b * T_SEQ;

    const int q0 = qt * 128;
    const int q_base = q0 + w * 32;

    // Q frags: rg in {0,1}, rows q_base + rg*16 + lr (already scaled by sc*log2e)
    bf16x8 qf[2][4];
#pragma unroll
    for (int rg = 0; rg < 2; ++rg) {
        const unsigned short* qrow = qb + (size_t)(b * T_SEQ + q_base + rg * 16 + lr) * DMODEL + h * DH;
#pragma unroll
        for (int c = 0; c < 4; ++c) qf[rg][c] = *(const bf16x8*)(qrow + c * 32 + lg * 8);
    }

    f32x4 o[2][8] = {{}};
    float m[2][4], lsum[2][4];
#pragma unroll
    for (int rg = 0; rg < 2; ++rg)
#pragma unroll
        for (int r = 0; r < 4; ++r) { m[rg][r] = -3.0e38f; lsum[rg][r] = 0.f; }

    const int nt = 2 * qt + 2;

    for (int kt = 0; kt < nt; ++kt) {
        const int k0 = kt * 64;
        __syncthreads();   // all reads of Ks/Vs from previous iter done
        // stage K tile (src pre-swizzled, LDS dest linear)
#pragma unroll
        for (int i = 0; i < 4; ++i) {
            int c = i * 256 + t;              // 16B chunk 0..1023
            int row = c >> 4;                 // 0..63
            int k16 = (c & 15) ^ (row & 7);
            GLL16(kbase + (size_t)(k0 + row) * DMODEL + k16 * 8, &Ks[c * 8]);
        }
        // stage V^T tile
#pragma unroll
        for (int i = 0; i < 4; ++i) {
            int c = i * 256 + t;              // 0..1023
            int d = c >> 3;                   // 0..127
            int k8 = (c & 7) ^ (d & 7);
            GLL16(vbase + (size_t)d * MTOT + k0 + k8 * 8, &Vs[c * 8]);
        }
        __syncthreads();   // vmcnt(0) drain: K,V landed

        // ---- S = Q K^T (both row-groups share kf reads) ----
        f32x4 s[2][4] = {{}};
        __builtin_amdgcn_s_setprio(1);
#pragma unroll
        for (int j = 0; j < 4; ++j) {
            const int krow = j * 16 + lr;
#pragma unroll
            for (int c = 0; c < 4; ++c) {
                bf16x8 kf = *(const bf16x8*)&Ks[krow * 128 + (((c * 4 + lg) ^ (krow & 7)) * 8)];
                s[0][j] = __builtin_amdgcn_mfma_f32_16x16x32_bf16(qf[0][c], kf, s[0][j], 0, 0, 0);
                s[1][j] = __builtin_amdgcn_mfma_f32_16x16x32_bf16(qf[1][c], kf, s[1][j], 0, 0, 0);
            }
        }
        __builtin_amdgcn_s_setprio(0);

        // ---- causal mask + online softmax (exp2 domain, defer-rescale) ----
#pragma unroll
        for (int rg = 0; rg < 2; ++rg) {
            const int qb0 = q_base + rg * 16;
            if (k0 + 63 > qb0) {
#pragma unroll
                for (int j = 0; j < 4; ++j) {
                    const int key = k0 + j * 16 + lr;
#pragma unroll
                    for (int r = 0; r < 4; ++r)
                        if (key > qb0 + lg * 4 + r) s[rg][j][r] = -3.0e38f;
                }
            }
            float tm[4];
            int need = 0;
#pragma unroll
            for (int r = 0; r < 4; ++r) {
                float v = fmaxf(fmaxf(s[rg][0][r], s[rg][1][r]), fmaxf(s[rg][2][r], s[rg][3][r]));
                tm[r] = red16_max(v);
                need |= (tm[r] - m[rg][r] > 8.0f) ? 1 : 0;
            }
            if (__any(need)) {
#pragma unroll
                for (int r = 0; r < 4; ++r) {
                    const float mn = fmaxf(m[rg][r], tm[r]);
                    const float a = EXP2F(m[rg][r] - mn);
                    m[rg][r] = mn;
                    lsum[rg][r] *= a;
#pragma unroll
                    for (int i = 0; i < 8; ++i) o[rg][i][r] *= a;
                }
            }
#pragma unroll
            for (int r = 0; r < 4; ++r) {
                float rs = 0.f;
#pragma unroll
                for (int j = 0; j < 4; ++j) { s[rg][j][r] = EXP2F(s[rg][j][r] - m[rg][r]); rs += s[rg][j][r]; }
                lsum[rg][r] += red16_sum(rs);
            }
        }

        // ---- P relayout (swizzled per-wave Ps, same-wave visibility) ----
        bf16x8 pa[2][2];
#pragma unroll
        for (int rg = 0; rg < 2; ++rg) {
#pragma unroll
            for (int j = 0; j < 4; ++j) {
#pragma unroll
                for (int r = 0; r < 4; ++r) {
                    const int prow = lg * 4 + r;
                    const int chunk = (j * 2 + (lr >> 3)) ^ (prow & 7);
                    Ps[w][prow][chunk * 8 + (lr & 7)] = f2bf(s[rg][j][r]);
                }
            }
#pragma unroll
            for (int kc = 0; kc < 2; ++kc)
                pa[rg][kc] = *(const bf16x8*)&Ps[w][lr][((kc * 4 + lg) ^ (lr & 7)) * 8];
        }

        // ---- O += P V (vf reads shared across row-groups) ----
        __builtin_amdgcn_s_setprio(1);
#pragma unroll
        for (int i = 0; i < 8; ++i) {
            const int d = i * 16 + lr;
#pragma unroll
            for (int kc = 0; kc < 2; ++kc) {
                bf16x8 vf = *(const bf16x8*)&Vs[d * 64 + (((kc * 4 + lg) ^ (d & 7)) * 8)];
                o[0][i] = __builtin_amdgcn_mfma_f32_16x16x32_bf16(pa[0][kc], vf, o[0][i], 0, 0, 0);
                o[1][i] = __builtin_amdgcn_mfma_f32_16x16x32_bf16(pa[1][kc], vf, o[1][i], 0, 0, 0);
            }
        }
        __builtin_amdgcn_s_setprio(0);
    }

    // ---- epilogue ----
#pragma unroll
    for (int rg = 0; rg < 2; ++rg) {
        float inv[4];
#pragma unroll
        for (int r = 0; r < 4; ++r) inv[r] = 1.f / lsum[rg][r];
#pragma unroll
        for (int i = 0; i < 8; ++i)
#pragma unroll
            for (int r = 0; r < 4; ++r)
                ob[(size_t)(b * T_SEQ + q_base + rg * 16 + lg * 4 + r) * DMODEL + h * DH + i * 16 + lr]
                    = f2bf(o[rg][i][r] * inv[r]);
    }
}

extern "C" void kernel_launch(void* const* d_in, const int* in_sizes, int n_in,
                              void* d_out, int out_size, void* d_ws, size_t ws_size,
                              hipStream_t stream) {
    const float* x      = (const float*)d_in[0];  // [4096, 2048]
    const float* wq     = (const float*)d_in[1];  // [2048, 2048]
    const float* w_down = (const float*)d_in[2];  // [2048, 1024]
    const float* w_up   = (const float*)d_in[3];  // [1024, 4096]
    const float* wo     = (const float*)d_in[4];  // [2048, 2048]
    float* out = (float*)d_out;

    uint8_t* p = (uint8_t*)d_ws;
    float* cosb = (float*)p;            p += (size_t)T_SEQ * 64 * 4;
    float* sinb = (float*)p;            p += (size_t)T_SEQ * 64 * 4;
    unsigned short* xb   = (unsigned short*)p; p += (size_t)MTOT * DMODEL * 2;
    unsigned short* wqT  = (unsigned short*)p; p += (size_t)DMODEL * DMODEL * 2;  // [2048][2048]
    unsigned short* wdT  = (unsigned short*)p; p += (size_t)DLAT * DMODEL * 2;    // [1024][2048], contiguous after wqT
    unsigned short* wuT  = (unsigned short*)p; p += (size_t)(2 * NH * DH) * DLAT * 2;
    unsigned short* woT  = (unsigned short*)p; p += (size_t)DMODEL * DMODEL * 2;
    unsigned short* qbuf = (unsigned short*)p; p += (size_t)MTOT * DMODEL * 2;
    unsigned short* ckv  = (unsigned short*)p; p += (size_t)MTOT * DLAT * 2;
    unsigned short* kbuf = (unsigned short*)p; p += (size_t)MTOT * DMODEL * 2;
    unsigned short* vbuf = (unsigned short*)p; p += (size_t)MTOT * DMODEL * 2;
    unsigned short* vT   = (unsigned short*)p; p += (size_t)DMODEL * MTOT * 2;
    unsigned short* abuf = xb;   // alias: xb dead after fused GEMM, abuf written after

    // prep: tables + conversions/transposes
    rope_table_kernel<<<(T_SEQ * 64) / 256, 256, 0, stream>>>(cosb, sinb);
    conv_f2b_kernel<<<(MTOT * DMODEL / 4) / 256, 256, 0, stream>>>(x, xb);
    transpose_all_kernel<<<14336, 256, 0, stream>>>(wq, w_down, w_up, wo, wqT, wdT, wuT, woT);

    // fused: [q | c_kv] = x @ [wq | w_down]  (wqT/wdT contiguous -> BT [3072][2048])
    gemm_bf16_kernel<4><<<dim3((DMODEL + DLAT) / 128, MTOT / 128), 256, 0, stream>>>(
        xb, wqT, qbuf, ckv, cosb, sinb, MTOT, DMODEL + DLAT, DMODEL);
    // kv_up = c_kv @ w_up -> k (rope) / v
    gemm_bf16_kernel<2><<<dim3((2 * NH * DH) / 128, MTOT / 128), 256, 0, stream>>>(
        ckv, wuT, kbuf, vbuf, cosb, sinb, MTOT, 2 * NH * DH, DLAT);
    // v -> v^T
    transpose_b2b_kernel<<<dim3(DMODEL / 32, MTOT / 32), 256, 0, stream>>>(vbuf, vT, MTOT, DMODEL);
    // attention (staged, LPT-ordered, 4 blocks/CU)
    attn_mfma2_kernel<<<dim3(BATCH * NH, 16), 256, 0, stream>>>(qbuf, kbuf, vT, abuf);
    // out = attn @ wo (fp32)
    gemm_bf16_kernel<3><<<dim3(DMODEL / 128, MTOT / 128), 256, 0, stream>>>(
        abuf, woT, out, nullptr, cosb, sinb, MTOT, DMODEL, DMODEL);
}

// Round 6
// 444.283 us; speedup vs baseline: 1.5460x; 1.5460x over previous
//
#include <hip/hip_runtime.h>
#include <math.h>
#include <stdint.h>

#define T_SEQ 2048
#define DMODEL 2048
#define DLAT 1024
#define NH 16
#define DH 128
#define BATCH 2
#define MTOT (BATCH * T_SEQ)   // 4096 rows total

typedef float f32x4 __attribute__((ext_vector_type(4)));
typedef __bf16 bf16x8 __attribute__((ext_vector_type(8)));

__device__ __forceinline__ unsigned short f2bf(float f) {
    return __builtin_bit_cast(unsigned short, (__bf16)f);   // RNE native cvt
}

#define EXP2F(x) __builtin_amdgcn_exp2f(x)

// 16-lane (row) reductions via DPP: quad_perm xor1, xor2, row_ror:4, row_ror:8
__device__ __forceinline__ float red16_max(float v) {
    int x = __builtin_bit_cast(int, v);
    v = fmaxf(v, __builtin_bit_cast(float, __builtin_amdgcn_update_dpp(x, x, 0xB1, 0xf, 0xf, false)));
    x = __builtin_bit_cast(int, v);
    v = fmaxf(v, __builtin_bit_cast(float, __builtin_amdgcn_update_dpp(x, x, 0x4E, 0xf, 0xf, false)));
    x = __builtin_bit_cast(int, v);
    v = fmaxf(v, __builtin_bit_cast(float, __builtin_amdgcn_update_dpp(x, x, 0x124, 0xf, 0xf, false)));
    x = __builtin_bit_cast(int, v);
    v = fmaxf(v, __builtin_bit_cast(float, __builtin_amdgcn_update_dpp(x, x, 0x128, 0xf, 0xf, false)));
    return v;
}
__device__ __forceinline__ float red16_sum(float v) {
    int x = __builtin_bit_cast(int, v);
    v += __builtin_bit_cast(float, __builtin_amdgcn_update_dpp(x, x, 0xB1, 0xf, 0xf, false));
    x = __builtin_bit_cast(int, v);
    v += __builtin_bit_cast(float, __builtin_amdgcn_update_dpp(x, x, 0x4E, 0xf, 0xf, false));
    x = __builtin_bit_cast(int, v);
    v += __builtin_bit_cast(float, __builtin_amdgcn_update_dpp(x, x, 0x124, 0xf, 0xf, false));
    x = __builtin_bit_cast(int, v);
    v += __builtin_bit_cast(float, __builtin_amdgcn_update_dpp(x, x, 0x128, 0xf, 0xf, false));
    return v;
}

// async global->LDS, 16B per lane (dest must be linear: wave base + lane*16)
#define GLL16(g, l) __builtin_amdgcn_global_load_lds( \
    (const __attribute__((address_space(1))) unsigned int*)(g), \
    (__attribute__((address_space(3))) unsigned int*)(l), 16, 0, 0)

// ---------------- RoPE tables: cos/sin [T][64] fp32 ----------------
__global__ void rope_table_kernel(float* __restrict__ cosb, float* __restrict__ sinb) {
    int idx = blockIdx.x * blockDim.x + threadIdx.x;
    if (idx >= T_SEQ * 64) return;
    int t = idx >> 6;
    int i = idx & 63;
    float inv = expf(-((2.0f * (float)i) / 128.0f) * logf(10000.0f));
    float ang = (float)t * inv;
    cosb[idx] = cosf(ang);
    sinb[idx] = sinf(ang);
}

// ---------------- fp32 -> bf16 elementwise (x) ----------------
__global__ void conv_f2b_kernel(const float* __restrict__ s, unsigned short* __restrict__ d) {
    int i = (blockIdx.x * blockDim.x + threadIdx.x) * 4;
    float4 v = *(const float4*)(s + i);
    ushort4 o;
    o.x = f2bf(v.x); o.y = f2bf(v.y); o.z = f2bf(v.z); o.w = f2bf(v.w);
    *(ushort4*)(d + i) = o;
}

// ---------------- all 4 weights: fp32 [R][C] -> bf16 [C][R] in one launch ----
// tiles: wq 4096 | w_down 2048 | w_up 4096 | wo 4096  (32x32 tiles, 256 thr)
__global__ __launch_bounds__(256)
void transpose_all_kernel(const float* __restrict__ wq, const float* __restrict__ wdn,
                          const float* __restrict__ wup, const float* __restrict__ wo,
                          unsigned short* __restrict__ wqT, unsigned short* __restrict__ wdT,
                          unsigned short* __restrict__ wuT, unsigned short* __restrict__ woT) {
    const int tile = blockIdx.x;
    const float* src; unsigned short* dst; int R, C, local;
    if (tile < 4096)       { src = wq;  dst = wqT; R = 2048; C = 2048; local = tile; }
    else if (tile < 6144)  { src = wdn; dst = wdT; R = 2048; C = 1024; local = tile - 4096; }
    else if (tile < 10240) { src = wup; dst = wuT; R = 1024; C = 4096; local = tile - 6144; }
    else                   { src = wo;  dst = woT; R = 2048; C = 2048; local = tile - 10240; }
    const int ctiles = C >> 5;
    const int c0 = (local & (ctiles - 1)) * 32;    // ctiles is pow2
    const int r0 = (local / ctiles) * 32;
    __shared__ unsigned short t16[32][33];
    const int tx = threadIdx.x & 31, ty = threadIdx.x >> 5;
#pragma unroll
    for (int i = 0; i < 32; i += 8)
        t16[ty + i][tx] = f2bf(src[(size_t)(r0 + ty + i) * C + c0 + tx]);
    __syncthreads();
#pragma unroll
    for (int i = 0; i < 32; i += 8)
        dst[(size_t)(c0 + ty + i) * R + r0 + tx] = t16[tx][ty + i];
}

// ---------------- bf16 [R][C] -> bf16 [C][R] transpose (V -> V^T) ----------------
__global__ void transpose_b2b_kernel(const unsigned short* __restrict__ src, unsigned short* __restrict__ dst,
                                     int R, int C) {
    __shared__ unsigned short tile[32][33];
    int tx = threadIdx.x & 31, ty = threadIdx.x >> 5;
    int r0 = blockIdx.y * 32, c0 = blockIdx.x * 32;
#pragma unroll
    for (int i = 0; i < 32; i += 8)
        tile[ty + i][tx] = src[(size_t)(r0 + ty + i) * C + c0 + tx];
    __syncthreads();
#pragma unroll
    for (int i = 0; i < 32; i += 8)
        dst[(size_t)(c0 + ty + i) * R + r0 + tx] = tile[tx][ty + i];
}

// ---------------- bf16 MFMA GEMM: C[M,N] = A[M,K] * BT[N,K]^T ----------------
// 128x128 tile, BK=32, 256 thr (4 waves 2x2), wave = 64x64 = 4x4 frags of 16x16x32.
// EPI: 2 = K(RoPE)/V split bf16, 3 = fp32 store,
//      4 = fused q/ckv: col<2048 -> RoPE -> *SC2 -> C0 (stride 2048); else -> C1 (stride 1024)
template <int EPI>
__global__ __launch_bounds__(256)
void gemm_bf16_kernel(const unsigned short* __restrict__ A, const unsigned short* __restrict__ BT,
                      void* __restrict__ C0, void* __restrict__ C1,
                      const float* __restrict__ cosb, const float* __restrict__ sinb,
                      int M, int N, int K) {
    __shared__ unsigned short As[128 * 32];
    __shared__ unsigned short Bs[128 * 32];
    const int t = threadIdx.x;
    const int w = t >> 6, l = t & 63;
    const int wr = w >> 1, wc = w & 1;
    const int lr = l & 15, lg = l >> 4;
    const int m0 = blockIdx.y * 128, n0 = blockIdx.x * 128;

    f32x4 acc[4][4] = {{}};

    const unsigned short* aP  = A  + (size_t)(m0 + (t >> 2)) * K + (t & 3) * 8;
    const unsigned short* aP2 = aP + (size_t)64 * K;
    const unsigned short* bP  = BT + (size_t)(n0 + (t >> 2)) * K + (t & 3) * 8;
    const unsigned short* bP2 = bP + (size_t)64 * K;

    for (int k0 = 0; k0 < K; k0 += 32) {
        __syncthreads();                       // protect previous iteration's reads
        GLL16(aP  + k0, &As[t * 8]);
        GLL16(aP2 + k0, &As[2048 + t * 8]);
        GLL16(bP  + k0, &Bs[t * 8]);
        GLL16(bP2 + k0, &Bs[2048 + t * 8]);
        __syncthreads();                       // drains vmcnt (loads landed)

        bf16x8 af[4], bfr[4];
#pragma unroll
        for (int i = 0; i < 4; ++i)
            af[i] = *(const bf16x8*)&As[(wr * 64 + i * 16 + lr) * 32 + lg * 8];
#pragma unroll
        for (int j = 0; j < 4; ++j)
            bfr[j] = *(const bf16x8*)&Bs[(wc * 64 + j * 16 + lr) * 32 + lg * 8];
#pragma unroll
        for (int i = 0; i < 4; ++i)
#pragma unroll
            for (int j = 0; j < 4; ++j)
                acc[i][j] = __builtin_amdgcn_mfma_f32_16x16x32_bf16(af[i], bfr[j], acc[i][j], 0, 0, 0);
    }

    const float SC2 = 0.08838834764831845f * 1.44269504089f;  // 1/sqrt(128)*log2e (q prescale)
    const bool is_v  = (EPI == 2) && ((n0 & 128) != 0);    // block-uniform
    const bool is_cv = (EPI == 4) && (n0 >= 2048);         // fused: c_kv half
#pragma unroll
    for (int i = 0; i < 4; ++i) {
#pragma unroll
        for (int j = 0; j < 4; ++j) {
#pragma unroll
            for (int rr = 0; rr < 4; ++rr) {
                const int row_g = m0 + wr * 64 + i * 16 + lg * 4 + rr;
                const int col_g = n0 + wc * 64 + j * 16 + lr;
                float v = acc[i][j][rr];
                if (EPI == 2) {
                    float res = v;
                    if (!is_v) {  // K half -> RoPE
                        float o_ = __shfl_xor(v, 1);
                        int d = col_g & 127;
                        int tp = row_g & (T_SEQ - 1);
                        float c = cosb[tp * 64 + (d >> 1)];
                        float s = sinb[tp * 64 + (d >> 1)];
                        res = (lr & 1) ? (o_ * s + v * c) : (v * c - o_ * s);
                    }
                    int dcol = ((col_g >> 8) << 7) | (col_g & 127);  // head*128 + d
                    unsigned short* dst = is_v ? (unsigned short*)C1 : (unsigned short*)C0;
                    dst[(size_t)row_g * DMODEL + dcol] = f2bf(res);
                } else if (EPI == 3) {  // fp32 final
                    ((float*)C0)[(size_t)row_g * N + col_g] = v;
                } else {  // EPI == 4 fused q / c_kv
                    if (!is_cv) {       // q half -> RoPE -> prescale -> C0 [.][2048]
                        float o_ = __shfl_xor(v, 1);
                        int d = col_g & 127;
                        int tp = row_g & (T_SEQ - 1);
                        float c = cosb[tp * 64 + (d >> 1)];
                        float s = sinb[tp * 64 + (d >> 1)];
                        float res = (lr & 1) ? (o_ * s + v * c) : (v * c - o_ * s);
                        ((unsigned short*)C0)[(size_t)row_g * DMODEL + col_g] = f2bf(res * SC2);
                    } else {            // c_kv -> C1 [.][1024]
                        ((unsigned short*)C1)[(size_t)row_g * DLAT + (col_g - 2048)] = f2bf(v);
                    }
                }
            }
        }
    }
}

// ---------------- staged bf16 MFMA causal flash attention ----------------
// grid (B*NH, 16), 256 thr = 4 waves, 128 q-rows/block. 64-key tiles, K+V
// single-buffered LDS (40KB -> 4 blocks/CU by LDS). launch_bounds min 2
// waves/EU: VGPR cap 256 -> ~116 alloc -> 4 waves/SIMD, NO SPILL (r5 lesson:
// min=4 capped VGPR at 64 and spilled accumulators -> 480MB scratch writes).
// XOR-swizzled LDS via pre-swizzled global_load_lds source. LPT order.
// Q pre-scaled by scale*log2e -> softmax in exp2 domain, defer-rescale THR=8,
// DPP row reductions, setprio around MFMA clusters.
__global__ __launch_bounds__(256, 2)
void attn_mfma2_kernel(const unsigned short* __restrict__ qb, const unsigned short* __restrict__ kb,
                       const unsigned short* __restrict__ vT, unsigned short* __restrict__ ob) {
    __shared__ __align__(16) unsigned short Ks[64 * 128];      // 16KB
    __shared__ __align__(16) unsigned short Vs[128 * 64];      // 16KB (V^T: d-major)
    __shared__ __align__(16) unsigned short Ps[4][16][64];     // 8KB, per-wave P buf

    const int bh = blockIdx.x;
    const int b = bh >> 4, h = bh & 15;
    const int qt = 15 - blockIdx.y;           // longest blocks first
    const int t = threadIdx.x;
    const int w = t >> 6, l = t & 63;
    const int lr = l & 15, lg = l >> 4;

    const unsigned short* kbase = kb + (size_t)(b * T_SEQ) * DMODEL + h * DH;
    const unsigned short* vbase = vT + (size_t)(h * DH) * MTOT + (size_t)b * T_SEQ;

    const int q0 = qt * 128;
    const int q_base = q0 + w * 32;

    // Q frags: rg in {0,1}, rows q_base + rg*16 + lr (already scaled by sc*log2e)
    bf16x8 qf[2][4];
#pragma unroll
    for (int rg = 0; rg < 2; ++rg) {
        const unsigned short* qrow = qb + (size_t)(b * T_SEQ + q_base + rg * 16 + lr) * DMODEL + h * DH;
#pragma unroll
        for (int c = 0; c < 4; ++c) qf[rg][c] = *(const bf16x8*)(qrow + c * 32 + lg * 8);
    }

    f32x4 o[2][8] = {{}};
    float m[2][4], lsum[2][4];
#pragma unroll
    for (int rg = 0; rg < 2; ++rg)
#pragma unroll
        for (int r = 0; r < 4; ++r) { m[rg][r] = -3.0e38f; lsum[rg][r] = 0.f; }

    const int nt = 2 * qt + 2;

    for (int kt = 0; kt < nt; ++kt) {
        const int k0 = kt * 64;
        __syncthreads();   // all reads of Ks/Vs from previous iter done
        // stage K tile (src pre-swizzled, LDS dest linear)
#pragma unroll
        for (int i = 0; i < 4; ++i) {
            int c = i * 256 + t;              // 16B chunk 0..1023
            int row = c >> 4;                 // 0..63
            int k16 = (c & 15) ^ (row & 7);
            GLL16(kbase + (size_t)(k0 + row) * DMODEL + k16 * 8, &Ks[c * 8]);
        }
        // stage V^T tile
#pragma unroll
        for (int i = 0; i < 4; ++i) {
            int c = i * 256 + t;              // 0..1023
            int d = c >> 3;                   // 0..127
            int k8 = (c & 7) ^ (d & 7);
            GLL16(vbase + (size_t)d * MTOT + k0 + k8 * 8, &Vs[c * 8]);
        }
        __syncthreads();   // vmcnt(0) drain: K,V landed

        // ---- S = Q K^T (both row-groups share kf reads) ----
        f32x4 s[2][4] = {{}};
        __builtin_amdgcn_s_setprio(1);
#pragma unroll
        for (int j = 0; j < 4; ++j) {
            const int krow = j * 16 + lr;
#pragma unroll
            for (int c = 0; c < 4; ++c) {
                bf16x8 kf = *(const bf16x8*)&Ks[krow * 128 + (((c * 4 + lg) ^ (krow & 7)) * 8)];
                s[0][j] = __builtin_amdgcn_mfma_f32_16x16x32_bf16(qf[0][c], kf, s[0][j], 0, 0, 0);
                s[1][j] = __builtin_amdgcn_mfma_f32_16x16x32_bf16(qf[1][c], kf, s[1][j], 0, 0, 0);
            }
        }
        __builtin_amdgcn_s_setprio(0);

        // ---- causal mask + online softmax (exp2 domain, defer-rescale) ----
#pragma unroll
        for (int rg = 0; rg < 2; ++rg) {
            const int qb0 = q_base + rg * 16;
            if (k0 + 63 > qb0) {
#pragma unroll
                for (int j = 0; j < 4; ++j) {
                    const int key = k0 + j * 16 + lr;
#pragma unroll
                    for (int r = 0; r < 4; ++r)
                        if (key > qb0 + lg * 4 + r) s[rg][j][r] = -3.0e38f;
                }
            }
            float tm[4];
            int need = 0;
#pragma unroll
            for (int r = 0; r < 4; ++r) {
                float v = fmaxf(fmaxf(s[rg][0][r], s[rg][1][r]), fmaxf(s[rg][2][r], s[rg][3][r]));
                tm[r] = red16_max(v);
                need |= (tm[r] - m[rg][r] > 8.0f) ? 1 : 0;
            }
            if (__any(need)) {
#pragma unroll
                for (int r = 0; r < 4; ++r) {
                    const float mn = fmaxf(m[rg][r], tm[r]);
                    const float a = EXP2F(m[rg][r] - mn);
                    m[rg][r] = mn;
                    lsum[rg][r] *= a;
#pragma unroll
                    for (int i = 0; i < 8; ++i) o[rg][i][r] *= a;
                }
            }
#pragma unroll
            for (int r = 0; r < 4; ++r) {
                float rs = 0.f;
#pragma unroll
                for (int j = 0; j < 4; ++j) { s[rg][j][r] = EXP2F(s[rg][j][r] - m[rg][r]); rs += s[rg][j][r]; }
                lsum[rg][r] += red16_sum(rs);
            }
        }

        // ---- P relayout (swizzled per-wave Ps, same-wave visibility) ----
        bf16x8 pa[2][2];
#pragma unroll
        for (int rg = 0; rg < 2; ++rg) {
#pragma unroll
            for (int j = 0; j < 4; ++j) {
#pragma unroll
                for (int r = 0; r < 4; ++r) {
                    const int prow = lg * 4 + r;
                    const int chunk = (j * 2 + (lr >> 3)) ^ (prow & 7);
                    Ps[w][prow][chunk * 8 + (lr & 7)] = f2bf(s[rg][j][r]);
                }
            }
#pragma unroll
            for (int kc = 0; kc < 2; ++kc)
                pa[rg][kc] = *(const bf16x8*)&Ps[w][lr][((kc * 4 + lg) ^ (lr & 7)) * 8];
        }

        // ---- O += P V (vf reads shared across row-groups) ----
        __builtin_amdgcn_s_setprio(1);
#pragma unroll
        for (int i = 0; i < 8; ++i) {
            const int d = i * 16 + lr;
#pragma unroll
            for (int kc = 0; kc < 2; ++kc) {
                bf16x8 vf = *(const bf16x8*)&Vs[d * 64 + (((kc * 4 + lg) ^ (d & 7)) * 8)];
                o[0][i] = __builtin_amdgcn_mfma_f32_16x16x32_bf16(pa[0][kc], vf, o[0][i], 0, 0, 0);
                o[1][i] = __builtin_amdgcn_mfma_f32_16x16x32_bf16(pa[1][kc], vf, o[1][i], 0, 0, 0);
            }
        }
        __builtin_amdgcn_s_setprio(0);
    }

    // ---- epilogue ----
#pragma unroll
    for (int rg = 0; rg < 2; ++rg) {
        float inv[4];
#pragma unroll
        for (int r = 0; r < 4; ++r) inv[r] = 1.f / lsum[rg][r];
#pragma unroll
        for (int i = 0; i < 8; ++i)
#pragma unroll
            for (int r = 0; r < 4; ++r)
                ob[(size_t)(b * T_SEQ + q_base + rg * 16 + lg * 4 + r) * DMODEL + h * DH + i * 16 + lr]
                    = f2bf(o[rg][i][r] * inv[r]);
    }
}

extern "C" void kernel_launch(void* const* d_in, const int* in_sizes, int n_in,
                              void* d_out, int out_size, void* d_ws, size_t ws_size,
                              hipStream_t stream) {
    const float* x      = (const float*)d_in[0];  // [4096, 2048]
    const float* wq     = (const float*)d_in[1];  // [2048, 2048]
    const float* w_down = (const float*)d_in[2];  // [2048, 1024]
    const float* w_up   = (const float*)d_in[3];  // [1024, 4096]
    const float* wo     = (const float*)d_in[4];  // [2048, 2048]
    float* out = (float*)d_out;

    uint8_t* p = (uint8_t*)d_ws;
    float* cosb = (float*)p;            p += (size_t)T_SEQ * 64 * 4;
    float* sinb = (float*)p;            p += (size_t)T_SEQ * 64 * 4;
    unsigned short* xb   = (unsigned short*)p; p += (size_t)MTOT * DMODEL * 2;
    unsigned short* wqT  = (unsigned short*)p; p += (size_t)DMODEL * DMODEL * 2;  // [2048][2048]
    unsigned short* wdT  = (unsigned short*)p; p += (size_t)DLAT * DMODEL * 2;    // [1024][2048], contiguous after wqT
    unsigned short* wuT  = (unsigned short*)p; p += (size_t)(2 * NH * DH) * DLAT * 2;
    unsigned short* woT  = (unsigned short*)p; p += (size_t)DMODEL * DMODEL * 2;
    unsigned short* qbuf = (unsigned short*)p; p += (size_t)MTOT * DMODEL * 2;
    unsigned short* ckv  = (unsigned short*)p; p += (size_t)MTOT * DLAT * 2;
    unsigned short* kbuf = (unsigned short*)p; p += (size_t)MTOT * DMODEL * 2;
    unsigned short* vbuf = (unsigned short*)p; p += (size_t)MTOT * DMODEL * 2;
    unsigned short* vT   = (unsigned short*)p; p += (size_t)DMODEL * MTOT * 2;
    unsigned short* abuf = xb;   // alias: xb dead after fused GEMM, abuf written after

    // prep: tables + conversions/transposes
    rope_table_kernel<<<(T_SEQ * 64) / 256, 256, 0, stream>>>(cosb, sinb);
    conv_f2b_kernel<<<(MTOT * DMODEL / 4) / 256, 256, 0, stream>>>(x, xb);
    transpose_all_kernel<<<14336, 256, 0, stream>>>(wq, w_down, w_up, wo, wqT, wdT, wuT, woT);

    // fused: [q | c_kv] = x @ [wq | w_down]  (wqT/wdT contiguous -> BT [3072][2048])
    gemm_bf16_kernel<4><<<dim3((DMODEL + DLAT) / 128, MTOT / 128), 256, 0, stream>>>(
        xb, wqT, qbuf, ckv, cosb, sinb, MTOT, DMODEL + DLAT, DMODEL);
    // kv_up = c_kv @ w_up -> k (rope) / v
    gemm_bf16_kernel<2><<<dim3((2 * NH * DH) / 128, MTOT / 128), 256, 0, stream>>>(
        ckv, wuT, kbuf, vbuf, cosb, sinb, MTOT, 2 * NH * DH, DLAT);
    // v -> v^T
    transpose_b2b_kernel<<<dim3(DMODEL / 32, MTOT / 32), 256, 0, stream>>>(vbuf, vT, MTOT, DMODEL);
    // attention (staged, LPT-ordered, 4 blocks/CU, no spill)
    attn_mfma2_kernel<<<dim3(BATCH * NH, 16), 256, 0, stream>>>(qbuf, kbuf, vT, abuf);
    // out = attn @ wo (fp32)
    gemm_bf16_kernel<3><<<dim3(DMODEL / 128, MTOT / 128), 256, 0, stream>>>(
        abuf, woT, out, nullptr, cosb, sinb, MTOT, DMODEL, DMODEL);
}

// Round 7
// 425.659 us; speedup vs baseline: 1.6136x; 1.0438x over previous
//
#include <hip/hip_runtime.h>
#include <math.h>
#include <stdint.h>

#define T_SEQ 2048
#define DMODEL 2048
#define DLAT 1024
#define NH 16
#define DH 128
#define BATCH 2
#define MTOT (BATCH * T_SEQ)   // 4096 rows total

typedef float f32x4 __attribute__((ext_vector_type(4)));
typedef __bf16 bf16x8 __attribute__((ext_vector_type(8)));

__device__ __forceinline__ unsigned short f2bf(float f) {
    return __builtin_bit_cast(unsigned short, (__bf16)f);   // RNE native cvt
}

#define EXP2F(x) __builtin_amdgcn_exp2f(x)

// 16-lane (row) reductions via DPP: quad_perm xor1, xor2, row_ror:4, row_ror:8
__device__ __forceinline__ float red16_max(float v) {
    int x = __builtin_bit_cast(int, v);
    v = fmaxf(v, __builtin_bit_cast(float, __builtin_amdgcn_update_dpp(x, x, 0xB1, 0xf, 0xf, false)));
    x = __builtin_bit_cast(int, v);
    v = fmaxf(v, __builtin_bit_cast(float, __builtin_amdgcn_update_dpp(x, x, 0x4E, 0xf, 0xf, false)));
    x = __builtin_bit_cast(int, v);
    v = fmaxf(v, __builtin_bit_cast(float, __builtin_amdgcn_update_dpp(x, x, 0x124, 0xf, 0xf, false)));
    x = __builtin_bit_cast(int, v);
    v = fmaxf(v, __builtin_bit_cast(float, __builtin_amdgcn_update_dpp(x, x, 0x128, 0xf, 0xf, false)));
    return v;
}
__device__ __forceinline__ float red16_sum(float v) {
    int x = __builtin_bit_cast(int, v);
    v += __builtin_bit_cast(float, __builtin_amdgcn_update_dpp(x, x, 0xB1, 0xf, 0xf, false));
    x = __builtin_bit_cast(int, v);
    v += __builtin_bit_cast(float, __builtin_amdgcn_update_dpp(x, x, 0x4E, 0xf, 0xf, false));
    x = __builtin_bit_cast(int, v);
    v += __builtin_bit_cast(float, __builtin_amdgcn_update_dpp(x, x, 0x124, 0xf, 0xf, false));
    x = __builtin_bit_cast(int, v);
    v += __builtin_bit_cast(float, __builtin_amdgcn_update_dpp(x, x, 0x128, 0xf, 0xf, false));
    return v;
}

// async global->LDS, 16B per lane (dest must be linear: wave base + lane*16)
#define GLL16(g, l) __builtin_amdgcn_global_load_lds( \
    (const __attribute__((address_space(1))) unsigned int*)(g), \
    (__attribute__((address_space(3))) unsigned int*)(l), 16, 0, 0)

// ---------------- RoPE tables: cos/sin [T][64] fp32 ----------------
__global__ void rope_table_kernel(float* __restrict__ cosb, float* __restrict__ sinb) {
    int idx = blockIdx.x * blockDim.x + threadIdx.x;
    if (idx >= T_SEQ * 64) return;
    int t = idx >> 6;
    int i = idx & 63;
    float inv = expf(-((2.0f * (float)i) / 128.0f) * logf(10000.0f));
    float ang = (float)t * inv;
    cosb[idx] = cosf(ang);
    sinb[idx] = sinf(ang);
}

// ---------------- fp32 -> bf16 elementwise (x) ----------------
__global__ void conv_f2b_kernel(const float* __restrict__ s, unsigned short* __restrict__ d) {
    int i = (blockIdx.x * blockDim.x + threadIdx.x) * 4;
    float4 v = *(const float4*)(s + i);
    ushort4 o;
    o.x = f2bf(v.x); o.y = f2bf(v.y); o.z = f2bf(v.z); o.w = f2bf(v.w);
    *(ushort4*)(d + i) = o;
}

// ---------------- all 4 weights: fp32 [R][C] -> bf16 [C][R] in one launch ----
__global__ __launch_bounds__(256)
void transpose_all_kernel(const float* __restrict__ wq, const float* __restrict__ wdn,
                          const float* __restrict__ wup, const float* __restrict__ wo,
                          unsigned short* __restrict__ wqT, unsigned short* __restrict__ wdT,
                          unsigned short* __restrict__ wuT, unsigned short* __restrict__ woT) {
    const int tile = blockIdx.x;
    const float* src; unsigned short* dst; int R, C, local;
    if (tile < 4096)       { src = wq;  dst = wqT; R = 2048; C = 2048; local = tile; }
    else if (tile < 6144)  { src = wdn; dst = wdT; R = 2048; C = 1024; local = tile - 4096; }
    else if (tile < 10240) { src = wup; dst = wuT; R = 1024; C = 4096; local = tile - 6144; }
    else                   { src = wo;  dst = woT; R = 2048; C = 2048; local = tile - 10240; }
    const int ctiles = C >> 5;
    const int c0 = (local & (ctiles - 1)) * 32;    // ctiles is pow2
    const int r0 = (local / ctiles) * 32;
    __shared__ unsigned short t16[32][33];
    const int tx = threadIdx.x & 31, ty = threadIdx.x >> 5;
#pragma unroll
    for (int i = 0; i < 32; i += 8)
        t16[ty + i][tx] = f2bf(src[(size_t)(r0 + ty + i) * C + c0 + tx]);
    __syncthreads();
#pragma unroll
    for (int i = 0; i < 32; i += 8)
        dst[(size_t)(c0 + ty + i) * R + r0 + tx] = t16[tx][ty + i];
}

// ---------------- bf16 [R][C] -> bf16 [C][R] transpose (V -> V^T) ----------------
__global__ void transpose_b2b_kernel(const unsigned short* __restrict__ src, unsigned short* __restrict__ dst,
                                     int R, int C) {
    __shared__ unsigned short tile[32][33];
    int tx = threadIdx.x & 31, ty = threadIdx.x >> 5;
    int r0 = blockIdx.y * 32, c0 = blockIdx.x * 32;
#pragma unroll
    for (int i = 0; i < 32; i += 8)
        tile[ty + i][tx] = src[(size_t)(r0 + ty + i) * C + c0 + tx];
    __syncthreads();
#pragma unroll
    for (int i = 0; i < 32; i += 8)
        dst[(size_t)(c0 + ty + i) * R + r0 + tx] = tile[tx][ty + i];
}

// ---------------- pipelined bf16 MFMA GEMM: C[M,N] = A[M,K] * BT[N,K]^T -------
// BM=128, BN=256, BK=32, 512 thr (8 waves 2m x 4n, 64x64 each, 4x4 frags).
// TRI-buffered LDS (72KB): compute tile t while staging tile t+2; counted
// s_waitcnt vmcnt(3) at tile end guarantees tile t+1 landed (never drain to 0
// in steady state); ONE raw s_barrier per K-tile. XOR swizzle (16B chunk
// c ^= ((c>>5)&1)<<1, == byte^=((byte>>9)&1)<<5) applied on the global source
// (gload_lds dest stays linear) and on the ds_read address.
// EPI: 2 = K(RoPE)/V split bf16, 3 = fp32 store, 4 = fused q(RoPE*SC2)/c_kv.
template <int EPI>
__global__ __launch_bounds__(512, 2)
void gemm8p_kernel(const unsigned short* __restrict__ A, const unsigned short* __restrict__ BT,
                   void* __restrict__ C0, void* __restrict__ C1,
                   const float* __restrict__ cosb, const float* __restrict__ sinb,
                   int M, int N, int K) {
    __shared__ __align__(16) unsigned short As3[3][128 * 32];   // 3 x 8KB
    __shared__ __align__(16) unsigned short Bs3[3][256 * 32];   // 3 x 16KB

    const int t = threadIdx.x;            // 0..511
    const int w = t >> 6, l = t & 63;
    const int wr = w >> 2, wc = w & 3;    // 2 x 4 waves
    const int lr = l & 15, lg = l >> 4;
    const int m0 = blockIdx.y * 128, n0 = blockIdx.x * 256;

    f32x4 acc[4][4] = {{}};
    const int nt = K >> 5;

    // stage K-tile kt into buffer buf: A 1 chunk/thr, B 2 chunks/thr (3 GLL16)
    auto stage = [&](int kt, int buf) {
        const int k0 = kt << 5;
        {
            int c = t;                                  // A chunk 0..511
            int cc = c ^ (((c >> 5) & 1) << 1);         // pre-swizzled source col
            GLL16(A + (size_t)(m0 + (c >> 2)) * K + k0 + (cc & 3) * 8, &As3[buf][c * 8]);
        }
#pragma unroll
        for (int u = 0; u < 2; ++u) {
            int c = t + u * 512;                        // B chunk 0..1023
            int cc = c ^ (((c >> 5) & 1) << 1);
            GLL16(BT + (size_t)(n0 + (c >> 2)) * K + k0 + (cc & 3) * 8, &Bs3[buf][c * 8]);
        }
    };

    // prologue: stage tiles 0,1; wait tile0 (3 loads of tile1 may stay in flight)
    stage(0, 0);
    stage(1, 1);
    asm volatile("s_waitcnt vmcnt(3)" ::: "memory");
    __builtin_amdgcn_sched_barrier(0);
    __builtin_amdgcn_s_barrier();
    __builtin_amdgcn_sched_barrier(0);

    int cur = 0;
    for (int kt = 0; kt < nt; ++kt) {
        const bool more = (kt + 2) < nt;
        if (more) {
            int nb = cur + 2; if (nb >= 3) nb -= 3;
            stage(kt + 2, nb);                          // writes buf of tile t-1 (reads done)
        }
        // ds_read fragments (swizzled addresses)
        bf16x8 af[4], bfr[4];
#pragma unroll
        for (int j = 0; j < 4; ++j) {
            int r = wc * 64 + j * 16 + lr;
            int c = (r << 2) + lg; c ^= (((c >> 5) & 1) << 1);
            bfr[j] = *(const bf16x8*)&Bs3[cur][c * 8];
        }
#pragma unroll
        for (int i = 0; i < 4; ++i) {
            int r = wr * 64 + i * 16 + lr;
            int c = (r << 2) + lg; c ^= (((c >> 5) & 1) << 1);
            af[i] = *(const bf16x8*)&As3[cur][c * 8];
        }
        __builtin_amdgcn_s_setprio(1);
#pragma unroll
        for (int i = 0; i < 4; ++i)
#pragma unroll
            for (int j = 0; j < 4; ++j)
                acc[i][j] = __builtin_amdgcn_mfma_f32_16x16x32_bf16(af[i], bfr[j], acc[i][j], 0, 0, 0);
        __builtin_amdgcn_s_setprio(0);
        __builtin_amdgcn_sched_barrier(0);
        if (more) asm volatile("s_waitcnt vmcnt(3)" ::: "memory");   // tile t+1 landed
        else      asm volatile("s_waitcnt vmcnt(0)" ::: "memory");   // epilogue drain
        __builtin_amdgcn_sched_barrier(0);
        __builtin_amdgcn_s_barrier();
        __builtin_amdgcn_sched_barrier(0);
        ++cur; if (cur == 3) cur = 0;
    }

    const float SC2 = 0.08838834764831845f * 1.44269504089f;  // 1/sqrt(128)*log2e
    const bool is_cv = (EPI == 4) && (n0 >= 2048);            // fused: c_kv cols
    const bool is_v2 = (EPI == 2) && (wc >= 2);               // kv_up: V half (wave-uniform)
#pragma unroll
    for (int i = 0; i < 4; ++i) {
#pragma unroll
        for (int j = 0; j < 4; ++j) {
#pragma unroll
            for (int rr = 0; rr < 4; ++rr) {
                const int row_g = m0 + wr * 64 + i * 16 + lg * 4 + rr;
                const int col_g = n0 + wc * 64 + j * 16 + lr;
                float v = acc[i][j][rr];
                if (EPI == 2) {
                    float res = v;
                    const int d = col_g & 127;
                    if (!is_v2) {  // K half -> RoPE
                        float o_ = __shfl_xor(v, 1);
                        int tp = row_g & (T_SEQ - 1);
                        float c = cosb[tp * 64 + (d >> 1)];
                        float s = sinb[tp * 64 + (d >> 1)];
                        res = (lr & 1) ? (o_ * s + v * c) : (v * c - o_ * s);
                    }
                    const int dcol = ((col_g >> 8) << 7) | d;   // head*128 + d
                    unsigned short* dst = is_v2 ? (unsigned short*)C1 : (unsigned short*)C0;
                    dst[(size_t)row_g * DMODEL + dcol] = f2bf(res);
                } else if (EPI == 3) {  // fp32 final
                    ((float*)C0)[(size_t)row_g * N + col_g] = v;
                } else {  // EPI == 4 fused q / c_kv
                    if (!is_cv) {       // q -> RoPE -> prescale
                        float o_ = __shfl_xor(v, 1);
                        int d = col_g & 127;
                        int tp = row_g & (T_SEQ - 1);
                        float c = cosb[tp * 64 + (d >> 1)];
                        float s = sinb[tp * 64 + (d >> 1)];
                        float res = (lr & 1) ? (o_ * s + v * c) : (v * c - o_ * s);
                        ((unsigned short*)C0)[(size_t)row_g * DMODEL + col_g] = f2bf(res * SC2);
                    } else {            // c_kv
                        ((unsigned short*)C1)[(size_t)row_g * DLAT + (col_g - 2048)] = f2bf(v);
                    }
                }
            }
        }
    }
}

// ---------------- staged bf16 MFMA causal flash attention ----------------
// (unchanged from round 6: 95us, VGPR 116, no spill)
__global__ __launch_bounds__(256, 2)
void attn_mfma2_kernel(const unsigned short* __restrict__ qb, const unsigned short* __restrict__ kb,
                       const unsigned short* __restrict__ vT, unsigned short* __restrict__ ob) {
    __shared__ __align__(16) unsigned short Ks[64 * 128];      // 16KB
    __shared__ __align__(16) unsigned short Vs[128 * 64];      // 16KB (V^T: d-major)
    __shared__ __align__(16) unsigned short Ps[4][16][64];     // 8KB, per-wave P buf

    const int bh = blockIdx.x;
    const int b = bh >> 4, h = bh & 15;
    const int qt = 15 - blockIdx.y;           // longest blocks first
    const int t = threadIdx.x;
    const int w = t >> 6, l = t & 63;
    const int lr = l & 15, lg = l >> 4;

    const unsigned short* kbase = kb + (size_t)(b * T_SEQ) * DMODEL + h * DH;
    const unsigned short* vbase = vT + (size_t)(h * DH) * MTOT + (size_t)b * T_SEQ;

    const int q0 = qt * 128;
    const int q_base = q0 + w * 32;

    bf16x8 qf[2][4];
#pragma unroll
    for (int rg = 0; rg < 2; ++rg) {
        const unsigned short* qrow = qb + (size_t)(b * T_SEQ + q_base + rg * 16 + lr) * DMODEL + h * DH;
#pragma unroll
        for (int c = 0; c < 4; ++c) qf[rg][c] = *(const bf16x8*)(qrow + c * 32 + lg * 8);
    }

    f32x4 o[2][8] = {{}};
    float m[2][4], lsum[2][4];
#pragma unroll
    for (int rg = 0; rg < 2; ++rg)
#pragma unroll
        for (int r = 0; r < 4; ++r) { m[rg][r] = -3.0e38f; lsum[rg][r] = 0.f; }

    const int nt = 2 * qt + 2;

    for (int kt = 0; kt < nt; ++kt) {
        const int k0 = kt * 64;
        __syncthreads();
#pragma unroll
        for (int i = 0; i < 4; ++i) {
            int c = i * 256 + t;
            int row = c >> 4;
            int k16 = (c & 15) ^ (row & 7);
            GLL16(kbase + (size_t)(k0 + row) * DMODEL + k16 * 8, &Ks[c * 8]);
        }
#pragma unroll
        for (int i = 0; i < 4; ++i) {
            int c = i * 256 + t;
            int d = c >> 3;
            int k8 = (c & 7) ^ (d & 7);
            GLL16(vbase + (size_t)d * MTOT + k0 + k8 * 8, &Vs[c * 8]);
        }
        __syncthreads();

        f32x4 s[2][4] = {{}};
        __builtin_amdgcn_s_setprio(1);
#pragma unroll
        for (int j = 0; j < 4; ++j) {
            const int krow = j * 16 + lr;
#pragma unroll
            for (int c = 0; c < 4; ++c) {
                bf16x8 kf = *(const bf16x8*)&Ks[krow * 128 + (((c * 4 + lg) ^ (krow & 7)) * 8)];
                s[0][j] = __builtin_amdgcn_mfma_f32_16x16x32_bf16(qf[0][c], kf, s[0][j], 0, 0, 0);
                s[1][j] = __builtin_amdgcn_mfma_f32_16x16x32_bf16(qf[1][c], kf, s[1][j], 0, 0, 0);
            }
        }
        __builtin_amdgcn_s_setprio(0);

#pragma unroll
        for (int rg = 0; rg < 2; ++rg) {
            const int qb0 = q_base + rg * 16;
            if (k0 + 63 > qb0) {
#pragma unroll
                for (int j = 0; j < 4; ++j) {
                    const int key = k0 + j * 16 + lr;
#pragma unroll
                    for (int r = 0; r < 4; ++r)
                        if (key > qb0 + lg * 4 + r) s[rg][j][r] = -3.0e38f;
                }
            }
            float tm[4];
            int need = 0;
#pragma unroll
            for (int r = 0; r < 4; ++r) {
                float v = fmaxf(fmaxf(s[rg][0][r], s[rg][1][r]), fmaxf(s[rg][2][r], s[rg][3][r]));
                tm[r] = red16_max(v);
                need |= (tm[r] - m[rg][r] > 8.0f) ? 1 : 0;
            }
            if (__any(need)) {
#pragma unroll
                for (int r = 0; r < 4; ++r) {
                    const float mn = fmaxf(m[rg][r], tm[r]);
                    const float a = EXP2F(m[rg][r] - mn);
                    m[rg][r] = mn;
                    lsum[rg][r] *= a;
#pragma unroll
                    for (int i = 0; i < 8; ++i) o[rg][i][r] *= a;
                }
            }
#pragma unroll
            for (int r = 0; r < 4; ++r) {
                float rs = 0.f;
#pragma unroll
                for (int j = 0; j < 4; ++j) { s[rg][j][r] = EXP2F(s[rg][j][r] - m[rg][r]); rs += s[rg][j][r]; }
                lsum[rg][r] += red16_sum(rs);
            }
        }

        bf16x8 pa[2][2];
#pragma unroll
        for (int rg = 0; rg < 2; ++rg) {
#pragma unroll
            for (int j = 0; j < 4; ++j) {
#pragma unroll
                for (int r = 0; r < 4; ++r) {
                    const int prow = lg * 4 + r;
                    const int chunk = (j * 2 + (lr >> 3)) ^ (prow & 7);
                    Ps[w][prow][chunk * 8 + (lr & 7)] = f2bf(s[rg][j][r]);
                }
            }
#pragma unroll
            for (int kc = 0; kc < 2; ++kc)
                pa[rg][kc] = *(const bf16x8*)&Ps[w][lr][((kc * 4 + lg) ^ (lr & 7)) * 8];
        }

        __builtin_amdgcn_s_setprio(1);
#pragma unroll
        for (int i = 0; i < 8; ++i) {
            const int d = i * 16 + lr;
#pragma unroll
            for (int kc = 0; kc < 2; ++kc) {
                bf16x8 vf = *(const bf16x8*)&Vs[d * 64 + (((kc * 4 + lg) ^ (d & 7)) * 8)];
                o[0][i] = __builtin_amdgcn_mfma_f32_16x16x32_bf16(pa[0][kc], vf, o[0][i], 0, 0, 0);
                o[1][i] = __builtin_amdgcn_mfma_f32_16x16x32_bf16(pa[1][kc], vf, o[1][i], 0, 0, 0);
            }
        }
        __builtin_amdgcn_s_setprio(0);
    }

#pragma unroll
    for (int rg = 0; rg < 2; ++rg) {
        float inv[4];
#pragma unroll
        for (int r = 0; r < 4; ++r) inv[r] = 1.f / lsum[rg][r];
#pragma unroll
        for (int i = 0; i < 8; ++i)
#pragma unroll
            for (int r = 0; r < 4; ++r)
                ob[(size_t)(b * T_SEQ + q_base + rg * 16 + lg * 4 + r) * DMODEL + h * DH + i * 16 + lr]
                    = f2bf(o[rg][i][r] * inv[r]);
    }
}

extern "C" void kernel_launch(void* const* d_in, const int* in_sizes, int n_in,
                              void* d_out, int out_size, void* d_ws, size_t ws_size,
                              hipStream_t stream) {
    const float* x      = (const float*)d_in[0];  // [4096, 2048]
    const float* wq     = (const float*)d_in[1];  // [2048, 2048]
    const float* w_down = (const float*)d_in[2];  // [2048, 1024]
    const float* w_up   = (const float*)d_in[3];  // [1024, 4096]
    const float* wo     = (const float*)d_in[4];  // [2048, 2048]
    float* out = (float*)d_out;

    uint8_t* p = (uint8_t*)d_ws;
    float* cosb = (float*)p;            p += (size_t)T_SEQ * 64 * 4;
    float* sinb = (float*)p;            p += (size_t)T_SEQ * 64 * 4;
    unsigned short* xb   = (unsigned short*)p; p += (size_t)MTOT * DMODEL * 2;
    unsigned short* wqT  = (unsigned short*)p; p += (size_t)DMODEL * DMODEL * 2;  // [2048][2048]
    unsigned short* wdT  = (unsigned short*)p; p += (size_t)DLAT * DMODEL * 2;    // [1024][2048], contiguous after wqT
    unsigned short* wuT  = (unsigned short*)p; p += (size_t)(2 * NH * DH) * DLAT * 2;
    unsigned short* woT  = (unsigned short*)p; p += (size_t)DMODEL * DMODEL * 2;
    unsigned short* qbuf = (unsigned short*)p; p += (size_t)MTOT * DMODEL * 2;
    unsigned short* ckv  = (unsigned short*)p; p += (size_t)MTOT * DLAT * 2;
    unsigned short* kbuf = (unsigned short*)p; p += (size_t)MTOT * DMODEL * 2;
    unsigned short* vbuf = (unsigned short*)p; p += (size_t)MTOT * DMODEL * 2;
    unsigned short* vT   = (unsigned short*)p; p += (size_t)DMODEL * MTOT * 2;
    unsigned short* abuf = xb;   // alias: xb dead after fused GEMM, abuf written after

    // prep: tables + conversions/transposes
    rope_table_kernel<<<(T_SEQ * 64) / 256, 256, 0, stream>>>(cosb, sinb);
    conv_f2b_kernel<<<(MTOT * DMODEL / 4) / 256, 256, 0, stream>>>(x, xb);
    transpose_all_kernel<<<14336, 256, 0, stream>>>(wq, w_down, w_up, wo, wqT, wdT, wuT, woT);

    // fused: [q | c_kv] = x @ [wq | w_down]  (wqT/wdT contiguous -> BT [3072][2048])
    gemm8p_kernel<4><<<dim3((DMODEL + DLAT) / 256, MTOT / 128), 512, 0, stream>>>(
        xb, wqT, qbuf, ckv, cosb, sinb, MTOT, DMODEL + DLAT, DMODEL);
    // kv_up = c_kv @ w_up -> k (rope) / v
    gemm8p_kernel<2><<<dim3((2 * NH * DH) / 256, MTOT / 128), 512, 0, stream>>>(
        ckv, wuT, kbuf, vbuf, cosb, sinb, MTOT, 2 * NH * DH, DLAT);
    // v -> v^T
    transpose_b2b_kernel<<<dim3(DMODEL / 32, MTOT / 32), 256, 0, stream>>>(vbuf, vT, MTOT, DMODEL);
    // attention (staged, LPT-ordered)
    attn_mfma2_kernel<<<dim3(BATCH * NH, 16), 256, 0, stream>>>(qbuf, kbuf, vT, abuf);
    // out = attn @ wo (fp32)
    gemm8p_kernel<3><<<dim3(DMODEL / 256, MTOT / 128), 512, 0, stream>>>(
        abuf, woT, out, nullptr, cosb, sinb, MTOT, DMODEL, DMODEL);
}

// Round 8
// 415.394 us; speedup vs baseline: 1.6535x; 1.0247x over previous
//
#include <hip/hip_runtime.h>
#include <math.h>
#include <stdint.h>

#define T_SEQ 2048
#define DMODEL 2048
#define DLAT 1024
#define NH 16
#define DH 128
#define BATCH 2
#define MTOT (BATCH * T_SEQ)   // 4096 rows total

typedef float f32x4 __attribute__((ext_vector_type(4)));
typedef __bf16 bf16x8 __attribute__((ext_vector_type(8)));

__device__ __forceinline__ unsigned short f2bf(float f) {
    return __builtin_bit_cast(unsigned short, (__bf16)f);   // RNE native cvt
}

#define EXP2F(x) __builtin_amdgcn_exp2f(x)

// 16-lane (row) reductions via DPP: quad_perm xor1, xor2, row_ror:4, row_ror:8
__device__ __forceinline__ float red16_max(float v) {
    int x = __builtin_bit_cast(int, v);
    v = fmaxf(v, __builtin_bit_cast(float, __builtin_amdgcn_update_dpp(x, x, 0xB1, 0xf, 0xf, false)));
    x = __builtin_bit_cast(int, v);
    v = fmaxf(v, __builtin_bit_cast(float, __builtin_amdgcn_update_dpp(x, x, 0x4E, 0xf, 0xf, false)));
    x = __builtin_bit_cast(int, v);
    v = fmaxf(v, __builtin_bit_cast(float, __builtin_amdgcn_update_dpp(x, x, 0x124, 0xf, 0xf, false)));
    x = __builtin_bit_cast(int, v);
    v = fmaxf(v, __builtin_bit_cast(float, __builtin_amdgcn_update_dpp(x, x, 0x128, 0xf, 0xf, false)));
    return v;
}
__device__ __forceinline__ float red16_sum(float v) {
    int x = __builtin_bit_cast(int, v);
    v += __builtin_bit_cast(float, __builtin_amdgcn_update_dpp(x, x, 0xB1, 0xf, 0xf, false));
    x = __builtin_bit_cast(int, v);
    v += __builtin_bit_cast(float, __builtin_amdgcn_update_dpp(x, x, 0x4E, 0xf, 0xf, false));
    x = __builtin_bit_cast(int, v);
    v += __builtin_bit_cast(float, __builtin_amdgcn_update_dpp(x, x, 0x124, 0xf, 0xf, false));
    x = __builtin_bit_cast(int, v);
    v += __builtin_bit_cast(float, __builtin_amdgcn_update_dpp(x, x, 0x128, 0xf, 0xf, false));
    return v;
}

// async global->LDS, 16B per lane (dest must be linear: wave base + lane*16)
#define GLL16(g, l) __builtin_amdgcn_global_load_lds( \
    (const __attribute__((address_space(1))) unsigned int*)(g), \
    (__attribute__((address_space(3))) unsigned int*)(l), 16, 0, 0)

// ---------------- RoPE tables: cos/sin [T][64] fp32 ----------------
__global__ void rope_table_kernel(float* __restrict__ cosb, float* __restrict__ sinb) {
    int idx = blockIdx.x * blockDim.x + threadIdx.x;
    if (idx >= T_SEQ * 64) return;
    int t = idx >> 6;
    int i = idx & 63;
    float inv = expf(-((2.0f * (float)i) / 128.0f) * logf(10000.0f));
    float ang = (float)t * inv;
    cosb[idx] = cosf(ang);
    sinb[idx] = sinf(ang);
}

// ---------------- fp32 -> bf16 elementwise (x) ----------------
__global__ void conv_f2b_kernel(const float* __restrict__ s, unsigned short* __restrict__ d) {
    int i = (blockIdx.x * blockDim.x + threadIdx.x) * 4;
    float4 v = *(const float4*)(s + i);
    ushort4 o;
    o.x = f2bf(v.x); o.y = f2bf(v.y); o.z = f2bf(v.z); o.w = f2bf(v.w);
    *(ushort4*)(d + i) = o;
}

// ---------------- all 4 weights: fp32 [R][C] -> bf16 [C][R] in one launch ----
__global__ __launch_bounds__(256)
void transpose_all_kernel(const float* __restrict__ wq, const float* __restrict__ wdn,
                          const float* __restrict__ wup, const float* __restrict__ wo,
                          unsigned short* __restrict__ wqT, unsigned short* __restrict__ wdT,
                          unsigned short* __restrict__ wuT, unsigned short* __restrict__ woT) {
    const int tile = blockIdx.x;
    const float* src; unsigned short* dst; int R, C, local;
    if (tile < 4096)       { src = wq;  dst = wqT; R = 2048; C = 2048; local = tile; }
    else if (tile < 6144)  { src = wdn; dst = wdT; R = 2048; C = 1024; local = tile - 4096; }
    else if (tile < 10240) { src = wup; dst = wuT; R = 1024; C = 4096; local = tile - 6144; }
    else                   { src = wo;  dst = woT; R = 2048; C = 2048; local = tile - 10240; }
    const int ctiles = C >> 5;
    const int c0 = (local & (ctiles - 1)) * 32;    // ctiles is pow2
    const int r0 = (local / ctiles) * 32;
    __shared__ unsigned short t16[32][33];
    const int tx = threadIdx.x & 31, ty = threadIdx.x >> 5;
#pragma unroll
    for (int i = 0; i < 32; i += 8)
        t16[ty + i][tx] = f2bf(src[(size_t)(r0 + ty + i) * C + c0 + tx]);
    __syncthreads();
#pragma unroll
    for (int i = 0; i < 32; i += 8)
        dst[(size_t)(c0 + ty + i) * R + r0 + tx] = t16[tx][ty + i];
}

// ---------------- bf16 [R][C] -> bf16 [C][R] transpose (V -> V^T) ----------------
__global__ void transpose_b2b_kernel(const unsigned short* __restrict__ src, unsigned short* __restrict__ dst,
                                     int R, int C) {
    __shared__ unsigned short tile[32][33];
    int tx = threadIdx.x & 31, ty = threadIdx.x >> 5;
    int r0 = blockIdx.y * 32, c0 = blockIdx.x * 32;
#pragma unroll
    for (int i = 0; i < 32; i += 8)
        tile[ty + i][tx] = src[(size_t)(r0 + ty + i) * C + c0 + tx];
    __syncthreads();
#pragma unroll
    for (int i = 0; i < 32; i += 8)
        dst[(size_t)(c0 + ty + i) * R + r0 + tx] = tile[tx][ty + i];
}

// ---------------- pipelined bf16 MFMA GEMM: C[M,N] = A[M,K] * BT[N,K]^T -------
// BM=128, BN=256, BK=64, 512 thr (8 waves 2m x 4n, 64x64 each, 4x4 frags).
// TRI-buffered LDS (144KB, 1 block/CU): compute tile t while staging t+2 into
// the buffer tile t-1 used (reads provably done). TWO sub-phases per K-tile
// (kk=0/1): {8 ds_read_b128 || stage || barrier || 16 MFMA || barrier} ->
// 4 barriers + 1 counted vmcnt(6) per 64 MFMA (2x better amortization than
// BK=32). Never drain vmcnt to 0 in steady state (6 loads/tile in flight).
// st_16x32-style XOR swizzle on global source + ds_read addr.
// XCD-aware bijective block swizzle (all grids %8==0), ntile-inner.
// EPI: 2 = K(RoPE)/V split bf16, 3 = fp32 store, 4 = fused q(RoPE*SC2)/c_kv.
template <int EPI>
__global__ __launch_bounds__(512, 2)
void gemm3p_kernel(const unsigned short* __restrict__ A, const unsigned short* __restrict__ BT,
                   void* __restrict__ C0, void* __restrict__ C1,
                   const float* __restrict__ cosb, const float* __restrict__ sinb,
                   int M, int N, int K) {
    __shared__ __align__(16) unsigned short AL[3][128 * 64];   // 3 x 16KB
    __shared__ __align__(16) unsigned short BL[3][256 * 64];   // 3 x 32KB

    const int t = threadIdx.x;            // 0..511
    const int w = t >> 6, l = t & 63;
    const int wr = w >> 2, wc = w & 3;    // 2 x 4 waves
    const int lr = l & 15, lg = l >> 4;

    // XCD-aware bijective swizzle; ntile-inner for A-panel L2 sharing
    const int gx = gridDim.x;
    const int nwg = gx * gridDim.y;
    const int bid = blockIdx.y * gx + blockIdx.x;
    const int sid = (bid & 7) * (nwg >> 3) + (bid >> 3);
    const int m0 = (sid / gx) * 128;
    const int n0 = (sid % gx) * 256;

    f32x4 acc[4][4] = {{}};
    const int nt = K >> 6;

    auto stageA = [&](int kt, int buf) {
        const int k0 = kt << 6;
#pragma unroll
        for (int u = 0; u < 2; ++u) {
            int c = t + (u << 9);                  // 0..1023: row=c>>3, chunk=c&7
            int row = c >> 3;
            int cc = (c & 7) ^ (((row >> 2) & 1) << 1);
            GLL16(A + (size_t)(m0 + row) * K + k0 + cc * 8, &AL[buf][c * 8]);
        }
    };
    auto stageB = [&](int kt, int buf, int half) {
        const int k0 = kt << 6;
#pragma unroll
        for (int u = 0; u < 2; ++u) {
            int c = t + (u << 9);
            int row = c >> 3;
            int cc = (c & 7) ^ (((row >> 2) & 1) << 1);
            GLL16(BT + (size_t)(n0 + half * 128 + row) * K + k0 + cc * 8,
                  &BL[buf][(half * 1024 + c) * 8]);
        }
    };

    // prologue: stage tiles 0,1 (6 loads each); wait tile0 only
    stageA(0, 0); stageB(0, 0, 0); stageB(0, 0, 1);
    stageA(1, 1); stageB(1, 1, 0); stageB(1, 1, 1);
    asm volatile("s_waitcnt vmcnt(6)" ::: "memory");
    __builtin_amdgcn_sched_barrier(0);
    __builtin_amdgcn_s_barrier();

    int cur = 0;
    for (int kt = 0; kt < nt; ++kt) {
        const bool more = (kt + 2) < nt;
        int nb = cur + 2; if (nb >= 3) nb -= 3;

#pragma unroll
        for (int kk = 0; kk < 2; ++kk) {
            // ds-read this kk-half's fragments (swizzled addr)
            bf16x8 af[4], bfr[4];
#pragma unroll
            for (int i = 0; i < 4; ++i) {
                int row = wr * 64 + i * 16 + lr;
                int ch = (kk * 4 + lg) ^ (((row >> 2) & 1) << 1);
                af[i] = *(const bf16x8*)&AL[cur][(row * 8 + ch) * 8];
            }
#pragma unroll
            for (int j = 0; j < 4; ++j) {
                int row = wc * 64 + j * 16 + lr;
                int ch = (kk * 4 + lg) ^ (((row >> 2) & 1) << 1);
                bfr[j] = *(const bf16x8*)&BL[cur][(row * 8 + ch) * 8];
            }
            // stage split across the two phases: 4 loads then 2
            if (more) {
                if (kk == 0) { stageA(kt + 2, nb); stageB(kt + 2, nb, 0); }
                else         { stageB(kt + 2, nb, 1); }
            }
            __builtin_amdgcn_s_barrier();          // phase gate (reads issued)
            __builtin_amdgcn_s_setprio(1);
#pragma unroll
            for (int i = 0; i < 4; ++i)
#pragma unroll
                for (int j = 0; j < 4; ++j)
                    acc[i][j] = __builtin_amdgcn_mfma_f32_16x16x32_bf16(af[i], bfr[j], acc[i][j], 0, 0, 0);
            __builtin_amdgcn_s_setprio(0);
            if (kk == 0) {
                __builtin_amdgcn_s_barrier();      // phase boundary
            } else {
                __builtin_amdgcn_sched_barrier(0);
                if (more) asm volatile("s_waitcnt vmcnt(6)" ::: "memory");  // tile t+1 landed
                else      asm volatile("s_waitcnt vmcnt(0)" ::: "memory");
                __builtin_amdgcn_sched_barrier(0);
                __builtin_amdgcn_s_barrier();      // tile boundary
            }
        }
        ++cur; if (cur == 3) cur = 0;
    }

    const float SC2 = 0.08838834764831845f * 1.44269504089f;  // 1/sqrt(128)*log2e
    const bool is_cv = (EPI == 4) && (n0 >= 2048);            // fused: c_kv cols
    const bool is_v2 = (EPI == 2) && (wc >= 2);               // kv_up: V half (wave-uniform)
#pragma unroll
    for (int i = 0; i < 4; ++i) {
#pragma unroll
        for (int j = 0; j < 4; ++j) {
#pragma unroll
            for (int rr = 0; rr < 4; ++rr) {
                const int row_g = m0 + wr * 64 + i * 16 + lg * 4 + rr;
                const int col_g = n0 + wc * 64 + j * 16 + lr;
                float v = acc[i][j][rr];
                if (EPI == 2) {
                    float res = v;
                    const int d = col_g & 127;
                    if (!is_v2) {  // K half -> RoPE
                        float o_ = __shfl_xor(v, 1);
                        int tp = row_g & (T_SEQ - 1);
                        float c = cosb[tp * 64 + (d >> 1)];
                        float s = sinb[tp * 64 + (d >> 1)];
                        res = (lr & 1) ? (o_ * s + v * c) : (v * c - o_ * s);
                    }
                    const int dcol = ((col_g >> 8) << 7) | d;   // head*128 + d
                    unsigned short* dst = is_v2 ? (unsigned short*)C1 : (unsigned short*)C0;
                    dst[(size_t)row_g * DMODEL + dcol] = f2bf(res);
                } else if (EPI == 3) {  // fp32 final
                    ((float*)C0)[(size_t)row_g * N + col_g] = v;
                } else {  // EPI == 4 fused q / c_kv
                    if (!is_cv) {       // q -> RoPE -> prescale
                        float o_ = __shfl_xor(v, 1);
                        int d = col_g & 127;
                        int tp = row_g & (T_SEQ - 1);
                        float c = cosb[tp * 64 + (d >> 1)];
                        float s = sinb[tp * 64 + (d >> 1)];
                        float res = (lr & 1) ? (o_ * s + v * c) : (v * c - o_ * s);
                        ((unsigned short*)C0)[(size_t)row_g * DMODEL + col_g] = f2bf(res * SC2);
                    } else {            // c_kv
                        ((unsigned short*)C1)[(size_t)row_g * DLAT + (col_g - 2048)] = f2bf(v);
                    }
                }
            }
        }
    }
}

// ---------------- staged bf16 MFMA causal flash attention ----------------
// QBLK=64 (was 128): grid (32 bh, 32 qtiles) = 1024 near-uniform blocks for
// better tail/occupancy (r7 measured 12.5% avg occupancy from LPT tail).
// Wave w owns rows qt*64 + w*16. 64-key tiles, K+V single-buffered (40KB).
// Q pre-scaled by scale*log2e; exp2-domain softmax, defer-rescale THR=8,
// DPP reductions, setprio MFMA. launch_bounds (256,2): no VGPR spill.
__global__ __launch_bounds__(256, 2)
void attn_mfma3_kernel(const unsigned short* __restrict__ qb, const unsigned short* __restrict__ kb,
                       const unsigned short* __restrict__ vT, unsigned short* __restrict__ ob) {
    __shared__ __align__(16) unsigned short Ks[64 * 128];      // 16KB
    __shared__ __align__(16) unsigned short Vs[128 * 64];      // 16KB (V^T: d-major)
    __shared__ __align__(16) unsigned short Ps[4][16][64];     // 8KB, per-wave P buf

    const int bh = blockIdx.x;
    const int b = bh >> 4, h = bh & 15;
    const int qt = 31 - blockIdx.y;           // longest blocks first
    const int t = threadIdx.x;
    const int w = t >> 6, l = t & 63;
    const int lr = l & 15, lg = l >> 4;

    const unsigned short* kbase = kb + (size_t)(b * T_SEQ) * DMODEL + h * DH;
    const unsigned short* vbase = vT + (size_t)(h * DH) * MTOT + (size_t)b * T_SEQ;

    const int q_base = qt * 64 + w * 16;

    bf16x8 qf[4];
    {
        const unsigned short* qrow = qb + (size_t)(b * T_SEQ + q_base + lr) * DMODEL + h * DH;
#pragma unroll
        for (int c = 0; c < 4; ++c) qf[c] = *(const bf16x8*)(qrow + c * 32 + lg * 8);
    }

    f32x4 o[8] = {};
    float m[4], lsum[4];
#pragma unroll
    for (int r = 0; r < 4; ++r) { m[r] = -3.0e38f; lsum[r] = 0.f; }

    const int nt = qt + 1;

    for (int kt = 0; kt < nt; ++kt) {
        const int k0 = kt * 64;
        __syncthreads();
#pragma unroll
        for (int i = 0; i < 4; ++i) {
            int c = i * 256 + t;
            int row = c >> 4;
            int k16 = (c & 15) ^ (row & 7);
            GLL16(kbase + (size_t)(k0 + row) * DMODEL + k16 * 8, &Ks[c * 8]);
        }
#pragma unroll
        for (int i = 0; i < 4; ++i) {
            int c = i * 256 + t;
            int d = c >> 3;
            int k8 = (c & 7) ^ (d & 7);
            GLL16(vbase + (size_t)d * MTOT + k0 + k8 * 8, &Vs[c * 8]);
        }
        __syncthreads();

        // ---- S = Q K^T ----
        f32x4 s[4] = {};
        __builtin_amdgcn_s_setprio(1);
#pragma unroll
        for (int j = 0; j < 4; ++j) {
            const int krow = j * 16 + lr;
#pragma unroll
            for (int c = 0; c < 4; ++c) {
                bf16x8 kf = *(const bf16x8*)&Ks[krow * 128 + (((c * 4 + lg) ^ (krow & 7)) * 8)];
                s[j] = __builtin_amdgcn_mfma_f32_16x16x32_bf16(qf[c], kf, s[j], 0, 0, 0);
            }
        }
        __builtin_amdgcn_s_setprio(0);

        // ---- causal mask + online softmax (exp2 domain, defer-rescale) ----
        if (k0 + 63 > q_base) {
#pragma unroll
            for (int j = 0; j < 4; ++j) {
                const int key = k0 + j * 16 + lr;
#pragma unroll
                for (int r = 0; r < 4; ++r)
                    if (key > q_base + lg * 4 + r) s[j][r] = -3.0e38f;
            }
        }
        float tm[4];
        int need = 0;
#pragma unroll
        for (int r = 0; r < 4; ++r) {
            float v = fmaxf(fmaxf(s[0][r], s[1][r]), fmaxf(s[2][r], s[3][r]));
            tm[r] = red16_max(v);
            need |= (tm[r] - m[r] > 8.0f) ? 1 : 0;
        }
        if (__any(need)) {
#pragma unroll
            for (int r = 0; r < 4; ++r) {
                const float mn = fmaxf(m[r], tm[r]);
                const float a = EXP2F(m[r] - mn);
                m[r] = mn;
                lsum[r] *= a;
#pragma unroll
                for (int i = 0; i < 8; ++i) o[i][r] *= a;
            }
        }
#pragma unroll
        for (int r = 0; r < 4; ++r) {
            float rs = 0.f;
#pragma unroll
            for (int j = 0; j < 4; ++j) { s[j][r] = EXP2F(s[j][r] - m[r]); rs += s[j][r]; }
            lsum[r] += red16_sum(rs);
        }

        // ---- P relayout (swizzled per-wave Ps, same-wave visibility) ----
        bf16x8 pa[2];
#pragma unroll
        for (int j = 0; j < 4; ++j) {
#pragma unroll
            for (int r = 0; r < 4; ++r) {
                const int prow = lg * 4 + r;
                const int chunk = (j * 2 + (lr >> 3)) ^ (prow & 7);
                Ps[w][prow][chunk * 8 + (lr & 7)] = f2bf(s[j][r]);
            }
        }
#pragma unroll
        for (int kc = 0; kc < 2; ++kc)
            pa[kc] = *(const bf16x8*)&Ps[w][lr][((kc * 4 + lg) ^ (lr & 7)) * 8];

        // ---- O += P V ----
        __builtin_amdgcn_s_setprio(1);
#pragma unroll
        for (int i = 0; i < 8; ++i) {
            const int d = i * 16 + lr;
#pragma unroll
            for (int kc = 0; kc < 2; ++kc) {
                bf16x8 vf = *(const bf16x8*)&Vs[d * 64 + (((kc * 4 + lg) ^ (d & 7)) * 8)];
                o[i] = __builtin_amdgcn_mfma_f32_16x16x32_bf16(pa[kc], vf, o[i], 0, 0, 0);
            }
        }
        __builtin_amdgcn_s_setprio(0);
    }

    // ---- epilogue ----
    float inv[4];
#pragma unroll
    for (int r = 0; r < 4; ++r) inv[r] = 1.f / lsum[r];
#pragma unroll
    for (int i = 0; i < 8; ++i)
#pragma unroll
        for (int r = 0; r < 4; ++r)
            ob[(size_t)(b * T_SEQ + q_base + lg * 4 + r) * DMODEL + h * DH + i * 16 + lr]
                = f2bf(o[i][r] * inv[r]);
}

extern "C" void kernel_launch(void* const* d_in, const int* in_sizes, int n_in,
                              void* d_out, int out_size, void* d_ws, size_t ws_size,
                              hipStream_t stream) {
    const float* x      = (const float*)d_in[0];  // [4096, 2048]
    const float* wq     = (const float*)d_in[1];  // [2048, 2048]
    const float* w_down = (const float*)d_in[2];  // [2048, 1024]
    const float* w_up   = (const float*)d_in[3];  // [1024, 4096]
    const float* wo     = (const float*)d_in[4];  // [2048, 2048]
    float* out = (float*)d_out;

    uint8_t* p = (uint8_t*)d_ws;
    float* cosb = (float*)p;            p += (size_t)T_SEQ * 64 * 4;
    float* sinb = (float*)p;            p += (size_t)T_SEQ * 64 * 4;
    unsigned short* xb   = (unsigned short*)p; p += (size_t)MTOT * DMODEL * 2;
    unsigned short* wqT  = (unsigned short*)p; p += (size_t)DMODEL * DMODEL * 2;  // [2048][2048]
    unsigned short* wdT  = (unsigned short*)p; p += (size_t)DLAT * DMODEL * 2;    // [1024][2048], contiguous after wqT
    unsigned short* wuT  = (unsigned short*)p; p += (size_t)(2 * NH * DH) * DLAT * 2;
    unsigned short* woT  = (unsigned short*)p; p += (size_t)DMODEL * DMODEL * 2;
    unsigned short* qbuf = (unsigned short*)p; p += (size_t)MTOT * DMODEL * 2;
    unsigned short* ckv  = (unsigned short*)p; p += (size_t)MTOT * DLAT * 2;
    unsigned short* kbuf = (unsigned short*)p; p += (size_t)MTOT * DMODEL * 2;
    unsigned short* vbuf = (unsigned short*)p; p += (size_t)MTOT * DMODEL * 2;
    unsigned short* vT   = (unsigned short*)p; p += (size_t)DMODEL * MTOT * 2;
    unsigned short* abuf = xb;   // alias: xb dead after fused GEMM, abuf written after

    // prep: tables + conversions/transposes
    rope_table_kernel<<<(T_SEQ * 64) / 256, 256, 0, stream>>>(cosb, sinb);
    conv_f2b_kernel<<<(MTOT * DMODEL / 4) / 256, 256, 0, stream>>>(x, xb);
    transpose_all_kernel<<<14336, 256, 0, stream>>>(wq, w_down, w_up, wo, wqT, wdT, wuT, woT);

    // fused: [q | c_kv] = x @ [wq | w_down]  (wqT/wdT contiguous -> BT [3072][2048])
    gemm3p_kernel<4><<<dim3((DMODEL + DLAT) / 256, MTOT / 128), 512, 0, stream>>>(
        xb, wqT, qbuf, ckv, cosb, sinb, MTOT, DMODEL + DLAT, DMODEL);
    // kv_up = c_kv @ w_up -> k (rope) / v
    gemm3p_kernel<2><<<dim3((2 * NH * DH) / 256, MTOT / 128), 512, 0, stream>>>(
        ckv, wuT, kbuf, vbuf, cosb, sinb, MTOT, 2 * NH * DH, DLAT);
    // v -> v^T
    transpose_b2b_kernel<<<dim3(DMODEL / 32, MTOT / 32), 256, 0, stream>>>(vbuf, vT, MTOT, DMODEL);
    // attention (QBLK=64, LPT-ordered, 1024 blocks)
    attn_mfma3_kernel<<<dim3(BATCH * NH, 32), 256, 0, stream>>>(qbuf, kbuf, vT, abuf);
    // out = attn @ wo (fp32)
    gemm3p_kernel<3><<<dim3(DMODEL / 256, MTOT / 128), 512, 0, stream>>>(
        abuf, woT, out, nullptr, cosb, sinb, MTOT, DMODEL, DMODEL);
}